// Round 6
// baseline (64.400 us; speedup 1.0000x reference)
//
#include <hip/hip_runtime.h>

// VecLocal2d via MFMA, R6: straight-line register pipeline, 4 pixels/block.
// R5 failure diagnosis: VGPR_Count=32 => abuf[2][5] never lived in registers
// (kc loop not fully unrolled -> runtime index -> scratch spill, rule #20).
// R6: macro-generated, named-register depth-3 A prefetch (no indexable
// arrays), 4 pixels per block (grid 256 = 1 block/CU, no rounds), W-LDS
// double-buffered so pixel p+1's W staging overlaps pixel p's MFMA loop.
//
// Pipeline (fast path, ~31.3 MB ws):
//   hz:   zero 132 halo planes of xc
//   t1:   x[bk][c][h][w] fp32 -> xc[(h+1)][(w+1)][bk][c] bf16 (34x34 halo)
//   main: per-pixel GEMM C[160][64] = X[160][288] * W[288][64], co bf16 out
//   t2:   out[bk][o][pix] = f32(co[pix][o][bk]) + bias[bk%10][o][pix]
// Fallback (ws < 31.3 MB): R3 path (proven, 10 MB).

#define HW    32
#define CIN   32
#define COUT  64
#define FDIM  288
#define FPAD  296
#define NBK   160
#define HP    34
#define PLANE (NBK * CIN)   // 5120 shorts per (ih,jw) plane

using f32x4  = __attribute__((ext_vector_type(4))) float;
using bf16x8 = __attribute__((ext_vector_type(8))) short;
using s16x4  = __attribute__((ext_vector_type(4))) short;

static __device__ inline unsigned short f2bf(float f) {
    unsigned u = __float_as_uint(f);
    u += 0x7FFFu + ((u >> 16) & 1u);   // round-to-nearest-even
    return (unsigned short)(u >> 16);
}
static constexpr size_t XC_BYTES = (size_t)HP * HP * PLANE * 2;       // 11,837,440
static constexpr size_t CO_BYTES = (size_t)1024 * COUT * NBK * 2;     // 20,971,520

// ---- hz ----
__global__ __launch_bounds__(256) void hz_kernel(short* __restrict__ xc)
{
    const int id = blockIdx.x;           // 0..131
    int h, w;
    if (id < 34)      { h = 0;  w = id; }
    else if (id < 68) { h = 33; w = id - 34; }
    else { const int e = id - 68; h = 1 + (e >> 1); w = (e & 1) * 33; }
    uint2* p = reinterpret_cast<uint2*>(xc + (size_t)(h * HP + w) * PLANE);
    const uint2 z = {0u, 0u};
#pragma unroll
    for (int r = 0; r < 5; ++r)
        p[threadIdx.x + r * 256] = z;
}

// ---- t1 ----
__global__ __launch_bounds__(256) void t1_kernel(
    const float* __restrict__ x, short* __restrict__ xc)
{
    __shared__ short tile[HW][36];
    const int bid = blockIdx.x;      // 5120 = bk(160) * h(32)
    const int bk  = bid >> 5;
    const int h   = bid & 31;
    const int tid = threadIdx.x;
    {
        const int c  = tid >> 3;
        const int w4 = (tid & 7) * 4;
        const float4 v = *reinterpret_cast<const float4*>(
            x + (size_t)(bk * 32 + c) * 1024 + h * 32 + w4);
        tile[w4 + 0][c] = (short)f2bf(v.x);
        tile[w4 + 1][c] = (short)f2bf(v.y);
        tile[w4 + 2][c] = (short)f2bf(v.z);
        tile[w4 + 3][c] = (short)f2bf(v.w);
    }
    __syncthreads();
    {
        const int w  = tid >> 3;
        const int cq = tid & 7;
        const uint2 pk = *reinterpret_cast<const uint2*>(&tile[w][cq * 4]);
        *reinterpret_cast<uint2*>(
            xc + (size_t)((h + 1) * HP + (w + 1)) * PLANE + bk * CIN + cq * 4) = pk;
    }
}

// ---- main ----
#define AOFF(kc, mt) ((((kc) / 3) * HP + ((kc) % 3)) * PLANE + (mt) * 16 * CIN)

#define LOADA5(v0, v1, v2, v3, v4, kc)                                   \
    v0 = *reinterpret_cast<const bf16x8*>(ap + AOFF(kc, 0));             \
    v1 = *reinterpret_cast<const bf16x8*>(ap + AOFF(kc, 1));             \
    v2 = *reinterpret_cast<const bf16x8*>(ap + AOFF(kc, 2));             \
    v3 = *reinterpret_cast<const bf16x8*>(ap + AOFF(kc, 3));             \
    v4 = *reinterpret_cast<const bf16x8*>(ap + AOFF(kc, 4));

#define MFMA5(v0, v1, v2, v3, v4, kc) {                                  \
    const bf16x8 b = *reinterpret_cast<const bf16x8*>(bp + (kc) * 32);   \
    acc0 = __builtin_amdgcn_mfma_f32_16x16x32_bf16(v0, b, acc0, 0, 0, 0);\
    acc1 = __builtin_amdgcn_mfma_f32_16x16x32_bf16(v1, b, acc1, 0, 0, 0);\
    acc2 = __builtin_amdgcn_mfma_f32_16x16x32_bf16(v2, b, acc2, 0, 0, 0);\
    acc3 = __builtin_amdgcn_mfma_f32_16x16x32_bf16(v3, b, acc3, 0, 0, 0);\
    acc4 = __builtin_amdgcn_mfma_f32_16x16x32_bf16(v4, b, acc4, 0, 0, 0);}

#define WLOAD(pp) {                                                      \
    const float* wp = w + (size_t)(pixbase + (pp)) * (COUT * FDIM);      \
    _Pragma("unroll")                                                    \
    for (int q = 0; q < 9; ++q) {                                        \
        const int g  = tid + q * 512;                                    \
        const int o2 = g / 72;                                           \
        const int f4 = (g - o2 * 72) * 4;                                \
        wv[q] = *reinterpret_cast<const float4*>(wp + o2 * FDIM + f4);   \
    } }

#define STORE1(a, mt) { s16x4 s;                                         \
    s.x = (short)f2bf(a[0]); s.y = (short)f2bf(a[1]);                    \
    s.z = (short)f2bf(a[2]); s.w = (short)f2bf(a[3]);                    \
    *reinterpret_cast<s16x4*>(co + cb + (mt) * 16) = s; }

#define PIXEL_BODY(p) {                                                  \
    /* scatter wv (loaded during pixel p-1) -> LDS buf p&1 */            \
    short* wb = &Wl[(p & 1) * (COUT * FPAD)];                            \
    _Pragma("unroll")                                                    \
    for (int q = 0; q < 9; ++q) {                                        \
        const int g  = tid + q * 512;                                    \
        const int o2 = g / 72;                                           \
        const int f4 = (g - o2 * 72) * 4;                                \
        const float vv[4] = {wv[q].x, wv[q].y, wv[q].z, wv[q].w};        \
        short* wrow = wb + o2 * FPAD;                                    \
        _Pragma("unroll")                                                \
        for (int e = 0; e < 4; ++e) {                                    \
            const int f = f4 + e; const int c = f / 9;                   \
            const int cell = f - c * 9;                                  \
            wrow[cell * 32 + c] = (short)f2bf(vv[e]); } }                \
    __syncthreads();                                                     \
    const short* ap = abase + (p) * PLANE;                               \
    const short* bp = wb + (nt * 16 + l15) * FPAD + lg8;                 \
    bf16x8 A0, A1, A2, A3, A4, B0, B1, B2, B3, B4, C0, C1, C2, C3, C4;  \
    LOADA5(A0, A1, A2, A3, A4, 0)                                        \
    LOADA5(B0, B1, B2, B3, B4, 1)                                        \
    LOADA5(C0, C1, C2, C3, C4, 2)                                        \
    MFMA5(A0, A1, A2, A3, A4, 0) LOADA5(A0, A1, A2, A3, A4, 3)           \
    MFMA5(B0, B1, B2, B3, B4, 1) LOADA5(B0, B1, B2, B3, B4, 4)           \
    if ((p) < 3) { WLOAD((p) + 1) }                                      \
    MFMA5(C0, C1, C2, C3, C4, 2) LOADA5(C0, C1, C2, C3, C4, 5)           \
    MFMA5(A0, A1, A2, A3, A4, 3) LOADA5(A0, A1, A2, A3, A4, 6)           \
    MFMA5(B0, B1, B2, B3, B4, 4) LOADA5(B0, B1, B2, B3, B4, 7)           \
    MFMA5(C0, C1, C2, C3, C4, 5) LOADA5(C0, C1, C2, C3, C4, 8)           \
    MFMA5(A0, A1, A2, A3, A4, 6)                                         \
    MFMA5(B0, B1, B2, B3, B4, 7)                                         \
    MFMA5(C0, C1, C2, C3, C4, 8)                                         \
    { const int o3 = nt * 16 + l15;                                      \
      const size_t cb = ((size_t)(pixbase + (p)) * COUT + o3) * NBK      \
                        + mh * 80 + (lane >> 4) * 4;                     \
      STORE1(acc0, 0) STORE1(acc1, 1) STORE1(acc2, 2)                    \
      STORE1(acc3, 3) STORE1(acc4, 4)                                    \
      acc0 = z4; acc1 = z4; acc2 = z4; acc3 = z4; acc4 = z4; } }

__global__ __launch_bounds__(512, 1) void local2d_main_kernel(
    const short* __restrict__ xc,
    const float* __restrict__ w,
    short* __restrict__ co)
{
    __shared__ short Wl[2 * COUT * FPAD];   // 75776 B, dbuf [o][cell*32+c]

    const int hb = blockIdx.x;              // 256 = i(32) * jq(8)
    const int lb = (hb & 7) * 32 + (hb >> 3);   // XCD-chunked, bijective
    const int i  = lb >> 3;
    const int jq = lb & 7;
    const int pixbase = i * 32 + jq * 4;
    const int tid = threadIdx.x;

    const int wave = tid >> 6;
    const int lane = tid & 63;
    const int nt   = wave & 3;        // N-tile (16 o)
    const int mh   = wave >> 2;       // M-half (80 bk)
    const int l15  = lane & 15;
    const int lg8  = (lane >> 4) * 8;

    const short* abase = xc + ((size_t)i * HP + jq * 4) * PLANE
                            + (mh * 80 + l15) * CIN + lg8;

    const f32x4 z4 = {0.f, 0.f, 0.f, 0.f};
    f32x4 acc0 = z4, acc1 = z4, acc2 = z4, acc3 = z4, acc4 = z4;
    float4 wv[9];

    WLOAD(0)
    PIXEL_BODY(0)
    PIXEL_BODY(1)
    PIXEL_BODY(2)
    PIXEL_BODY(3)
}

// ---- t2 ----
__global__ __launch_bounds__(256) void t2_kernel(
    const short* __restrict__ co,
    const float* __restrict__ bias,
    float* __restrict__ out)
{
    __shared__ short tl[32][36];
    const int b    = blockIdx.x;          // 10240 = o(64) * bkT(5) * pixT(32)
    const int o    = b & 63;
    const int rest = b >> 6;
    const int bkT  = rest % 5;
    const int pixT = rest / 5;
    const int tid  = threadIdx.x;
    {
        const int p  = tid >> 3;
        const int bq = tid & 7;
        const int pix = pixT * 32 + p;
        const s16x4 v = *reinterpret_cast<const s16x4*>(
            co + ((size_t)pix * COUT + o) * NBK + bkT * 32 + bq * 4);
        *reinterpret_cast<s16x4*>(&tl[p][bq * 4]) = v;
    }
    __syncthreads();
    {
        const int bb = tid >> 3;
        const int pq = tid & 7;
        const int bk = bkT * 32 + bb;
        const int k  = bk % 10;
        const size_t pbase = (size_t)pixT * 32 + pq * 4;
        const float4 bv = *reinterpret_cast<const float4*>(
            bias + ((size_t)(k * COUT + o) << 10) + pbase);
        float4 r;
        r.x = __uint_as_float(((unsigned)(unsigned short)tl[pq * 4 + 0][bb]) << 16) + bv.x;
        r.y = __uint_as_float(((unsigned)(unsigned short)tl[pq * 4 + 1][bb]) << 16) + bv.y;
        r.z = __uint_as_float(((unsigned)(unsigned short)tl[pq * 4 + 2][bb]) << 16) + bv.z;
        r.w = __uint_as_float(((unsigned)(unsigned short)tl[pq * 4 + 3][bb]) << 16) + bv.w;
        *reinterpret_cast<float4*>(out + ((size_t)(bk * COUT + o) << 10) + pbase) = r;
    }
}

// ================= R3 fallback (proven; needs 10 MB ws) =================
__global__ __launch_bounds__(256) void xpose_kernel(
    const float* __restrict__ x, short* __restrict__ xc)
{
    __shared__ short tile[HW][36];
    const int bid = blockIdx.x;
    const int bk  = bid >> 5;
    const int h   = bid & 31;
    const int tid = threadIdx.x;
    {
        const int c  = tid >> 3;
        const int w4 = (tid & 7) * 4;
        const float4 v = *reinterpret_cast<const float4*>(
            x + (size_t)(bk * 32 + c) * 1024 + h * 32 + w4);
        tile[w4 + 0][c] = (short)f2bf(v.x);
        tile[w4 + 1][c] = (short)f2bf(v.y);
        tile[w4 + 2][c] = (short)f2bf(v.z);
        tile[w4 + 3][c] = (short)f2bf(v.w);
    }
    __syncthreads();
    {
        const int w  = tid >> 3;
        const int cq = tid & 7;
        const uint2 pk = *reinterpret_cast<const uint2*>(&tile[w][cq * 4]);
        *reinterpret_cast<uint2*>(
            xc + ((size_t)(bk * 1024 + h * 32 + w) * 32 + cq * 4)) = pk;
    }
}

__global__ __launch_bounds__(512, 4) void local2d_mfma2_kernel(
    const short* __restrict__ xc,
    const float* __restrict__ w,
    const float* __restrict__ bias,
    float* __restrict__ out)
{
    __shared__ short Wl[COUT * FPAD];
    const int hb  = blockIdx.x;
    const int lb  = (hb & 7) * 128 + (hb >> 3);
    const int i   = lb >> 5;
    const int j   = lb & 31;
    const int pix = i * HW + j;
    const int tid = threadIdx.x;
    {
        const float* wp = w + (size_t)pix * (COUT * FDIM);
#pragma unroll
        for (int p = 0; p < 9; ++p) {
            const int g  = tid + p * 512;
            const int o  = g / 72;
            const int f4 = (g - o * 72) * 4;
            const float4 v = *reinterpret_cast<const float4*>(wp + o * FDIM + f4);
            const float vv[4] = {v.x, v.y, v.z, v.w};
            short* wrow = &Wl[o * FPAD];
#pragma unroll
            for (int e = 0; e < 4; ++e) {
                const int f    = f4 + e;
                const int c    = f / 9;
                const int cell = f - c * 9;
                wrow[cell * 32 + c] = (short)f2bf(vv[e]);
            }
        }
    }
    __syncthreads();
    const int wave = tid >> 6;
    const int lane = tid & 63;
    const int nt   = wave & 3;
    const int mh   = wave >> 2;
    const int l15  = lane & 15;
    const int lg8  = (lane >> 4) * 8;
    f32x4 acc[5];
#pragma unroll
    for (int mt = 0; mt < 5; ++mt)
#pragma unroll
        for (int r = 0; r < 4; ++r) acc[mt][r] = 0.f;
    const short* xb[5];
#pragma unroll
    for (int mt = 0; mt < 5; ++mt) {
        const int bk = mh * 80 + mt * 16 + l15;
        xb[mt] = xc + (size_t)bk * (HW * HW * CIN) + lg8;
    }
    const short* bp = &Wl[(nt * 16 + l15) * FPAD + lg8];
#pragma unroll
    for (int kc = 0; kc < 9; ++kc) {
        const int kh = kc / 3;
        const int kw = kc - kh * 3;
        const int ih = i - 1 + kh;
        const int jw = j - 1 + kw;
        if ((unsigned)ih >= (unsigned)HW || (unsigned)jw >= (unsigned)HW)
            continue;
        const bf16x8 b = *reinterpret_cast<const bf16x8*>(bp + kc * 32);
        const int xoff = (ih * HW + jw) * CIN;
#pragma unroll
        for (int mt = 0; mt < 5; ++mt) {
            const bf16x8 a = *reinterpret_cast<const bf16x8*>(xb[mt] + xoff);
            acc[mt] = __builtin_amdgcn_mfma_f32_16x16x32_bf16(a, b, acc[mt], 0, 0, 0);
        }
    }
    const int o  = nt * 16 + l15;
    const int r0 = (lane >> 4) * 4;
#pragma unroll
    for (int mt = 0; mt < 5; ++mt) {
        const int bk0 = mh * 80 + mt * 16 + r0;
#pragma unroll
        for (int r = 0; r < 4; ++r) {
            const int bk = bk0 + r;
            const int k  = bk % 10;
            out[((size_t)(bk * COUT + o) << 10) + pix] =
                acc[mt][r] + bias[((size_t)(k * COUT + o) << 10) + pix];
        }
    }
}

extern "C" void kernel_launch(void* const* d_in, const int* in_sizes, int n_in,
                              void* d_out, int out_size, void* d_ws, size_t ws_size,
                              hipStream_t stream) {
    const float* x    = (const float*)d_in[0];
    const float* w    = (const float*)d_in[1];
    const float* bias = (const float*)d_in[2];
    float* out        = (float*)d_out;

    if (ws_size >= XC_BYTES + CO_BYTES) {
        short* xc = (short*)d_ws;
        short* co = (short*)((char*)d_ws + XC_BYTES);
        hipLaunchKernelGGL(hz_kernel, dim3(132), dim3(256), 0, stream, xc);
        hipLaunchKernelGGL(t1_kernel, dim3(5120), dim3(256), 0, stream, x, xc);
        hipLaunchKernelGGL(local2d_main_kernel, dim3(256), dim3(512), 0, stream,
                           xc, w, co);
        hipLaunchKernelGGL(t2_kernel, dim3(10240), dim3(256), 0, stream,
                           co, bias, out);
    } else {
        short* xc = (short*)d_ws;
        hipLaunchKernelGGL(xpose_kernel, dim3(5120), dim3(256), 0, stream, x, xc);
        hipLaunchKernelGGL(local2d_mfma2_kernel, dim3(1024), dim3(512), 0, stream,
                           xc, w, bias, out);
    }
}

// Round 7
// 52.440 us; speedup vs baseline: 1.2281x; 1.2281x over previous
//
#include <hip/hip_runtime.h>

// VecLocal2d via MFMA, R7: LDS-staged A-panel (kills the 4x redundant L3
// traffic that capped R4-R6 at ~50us), circular jw-slot buffer, swizzled
// global_load_lds staging, lgkm-only compute waits.
//
// Pipeline (fast path, ~31.3 MB ws):
//   hz:   zero halo planes of xc
//   t1:   x[bk][c][h][w] fp32 -> xc[(h+1)][(w+1)][bk][c] bf16, PER-PLANE
//         PRE-SWIZZLED: in-plane offset ^= ((bk>>1)&3)<<4  (rule #21: linear
//         gl_lds dest + inverse-swizzled source + swizzled ds_read)
//   main: 4 pixels/block (grid 256). A: 4-slot circular [jw][kh][bk][c] LDS
//         buffer staged by global_load_lds(16B); adjacent pixels share 2/3
//         planes -> 1 slot restaged per pixel, overlapped with compute.
//         W: fp32->bf16 LDS [o][cell*32+c] (wv regs loaded one pixel ahead).
//         Compute: 45 ds_read_b128(A) + 9(B) + 45 mfma_16x16x32_bf16.
//   t2:   out[bk][o][pix] = f32(co[pix][o][bk]) + bias[bk%10][o][pix]
// Fallback (ws < 31.3 MB): R3 path (proven, 10 MB, unswizzled).

#define HW    32
#define CIN   32
#define COUT  64
#define FDIM  288
#define FPAD  296
#define NBK   160
#define HP    34
#define PLANE (NBK * CIN)      // 5120 shorts = 10240 B per (ih,jw) plane
#define SLOT_SH (3 * PLANE)    // 15360 shorts per jw-slot (3 kh planes)
#define WOFF  (4 * SLOT_SH)    // 61440 shorts: W region start

using f32x4  = __attribute__((ext_vector_type(4))) float;
using bf16x8 = __attribute__((ext_vector_type(8))) short;
using s16x4  = __attribute__((ext_vector_type(4))) short;

static __device__ inline unsigned short f2bf(float f) {
    unsigned u = __float_as_uint(f);
    u += 0x7FFFu + ((u >> 16) & 1u);   // round-to-nearest-even
    return (unsigned short)(u >> 16);
}
static __device__ inline void gl_lds16(const short* src, short* dst) {
    __builtin_amdgcn_global_load_lds(
        (const __attribute__((address_space(1))) unsigned int*)src,
        (__attribute__((address_space(3))) unsigned int*)dst, 16, 0, 0);
}
static constexpr size_t XC_BYTES = (size_t)HP * HP * PLANE * 2;       // 11,837,440
static constexpr size_t CO_BYTES = (size_t)1024 * COUT * NBK * 2;     // 20,971,520

// ---- hz: zero halo planes ----
__global__ __launch_bounds__(256) void hz_kernel(short* __restrict__ xc)
{
    const int id = blockIdx.x;           // 0..131
    int h, w;
    if (id < 34)      { h = 0;  w = id; }
    else if (id < 68) { h = 33; w = id - 34; }
    else { const int e = id - 68; h = 1 + (e >> 1); w = (e & 1) * 33; }
    uint2* p = reinterpret_cast<uint2*>(xc + (size_t)(h * HP + w) * PLANE);
    const uint2 z = {0u, 0u};
#pragma unroll
    for (int r = 0; r < 5; ++r)
        p[threadIdx.x + r * 256] = z;
}

// ---- t1: x -> xc (halo layout, PRE-SWIZZLED in-plane) ----
__global__ __launch_bounds__(256) void t1_kernel(
    const float* __restrict__ x, short* __restrict__ xc)
{
    __shared__ short tile[HW][36];
    const int bid = blockIdx.x;      // 5120 = bk(160) * h(32)
    const int bk  = bid >> 5;
    const int h   = bid & 31;
    const int tid = threadIdx.x;
    {
        const int c  = tid >> 3;
        const int w4 = (tid & 7) * 4;
        const float4 v = *reinterpret_cast<const float4*>(
            x + (size_t)(bk * 32 + c) * 1024 + h * 32 + w4);
        tile[w4 + 0][c] = (short)f2bf(v.x);
        tile[w4 + 1][c] = (short)f2bf(v.y);
        tile[w4 + 2][c] = (short)f2bf(v.z);
        tile[w4 + 3][c] = (short)f2bf(v.w);
    }
    __syncthreads();
    {
        const int w  = tid >> 3;
        const int cq = tid & 7;
        const uint2 pk = *reinterpret_cast<const uint2*>(&tile[w][cq * 4]);
        // in-plane short idx: bk*32 + cq*4, swizzled (byte bits 4-5 -> short bits 3-4)
        const int sidx = bk * 32 + ((cq * 4) ^ (((bk >> 1) & 3) << 3));
        *reinterpret_cast<uint2*>(
            xc + (size_t)((h + 1) * HP + (w + 1)) * PLANE + sidx) = pk;
    }
}

// ---- main ----
__global__ __launch_bounds__(512) void local2d_main_kernel(
    const short* __restrict__ xc,
    const float* __restrict__ w,
    short* __restrict__ co)
{
    __shared__ __align__(1024) short Sl[WOFF + COUT * FPAD];  // 160,768 B

    const int hb = blockIdx.x;                  // 256 = i(32) * jt(8)
    const int lb = (hb & 7) * 32 + (hb >> 3);   // XCD-chunked, bijective
    const int i  = lb >> 3;
    const int jt = lb & 7;
    const int j0 = jt * 4;
    const int tid = threadIdx.x;

    const int wave = tid >> 6;
    const int lane = tid & 63;
    const int nt   = wave & 3;        // N-tile (16 o)
    const int mh   = wave >> 2;       // M-half (80 bk)
    const int l15  = lane & 15;
    const int lg   = lane >> 4;
    const int lg8  = lg * 8;

    short* WL = Sl + WOFF;

    // per-lane A row-bytes (swizzled), loop-invariant
    int rowbyte[5];
#pragma unroll
    for (int mt = 0; mt < 5; ++mt) {
        const int bk = mh * 80 + mt * 16 + l15;
        rowbyte[mt] = (bk * 64 + lg * 16) ^ (((bk >> 1) & 3) << 4);
    }

    float4 wv[9];
#define WLOAD(pp) {                                                        \
        const float* wp = w + (size_t)((i * 32) + j0 + (pp)) * (COUT * FDIM); \
        _Pragma("unroll")                                                  \
        for (int q = 0; q < 9; ++q) {                                      \
            const int g  = tid + q * 512;                                  \
            const int o2 = g / 72;                                         \
            const int f4 = (g - o2 * 72) * 4;                              \
            wv[q] = *reinterpret_cast<const float4*>(wp + o2 * FDIM + f4); \
        } }

    // ---- prologue: W(0) regs + stage all 4 A-slots (jw_xc = j0..j0+3) ----
    WLOAD(0)
    {
#pragma unroll
        for (int r = 0; r < 15; ++r) {         // 7680 16B-chunks / 512 thr
            const int u   = tid + r * 512;
            const int s   = u / 1920;
            const int rem = u - s * 1920;
            const int pl  = rem / 640;
            const int cu  = rem - pl * 640;
            const short* src = xc + (size_t)((i + pl) * HP + (j0 + s)) * PLANE + cu * 8;
            gl_lds16(src, Sl + (size_t)u * 8);
        }
    }

    const f32x4 z4 = {0.f, 0.f, 0.f, 0.f};

#pragma unroll
    for (int p = 0; p < 4; ++p) {
        // ---- scatter wv (pixel p's W) -> W LDS ----
#pragma unroll
        for (int q = 0; q < 9; ++q) {
            const int g  = tid + q * 512;
            const int o2 = g / 72;
            const int f4 = (g - o2 * 72) * 4;
            const float vv[4] = {wv[q].x, wv[q].y, wv[q].z, wv[q].w};
            short* wrow = WL + o2 * FPAD;
#pragma unroll
            for (int e = 0; e < 4; ++e) {
                const int f = f4 + e; const int c = f / 9;
                const int cell = f - c * 9;
                wrow[cell * 32 + c] = (short)f2bf(vv[e]);
            }
        }
        __syncthreads();

        // ---- issue next-pixel W loads + A-slot restage (drain at NEXT barrier) ----
        if (p < 3) WLOAD(p + 1)
        if (p == 1 || p == 2) {
            const int s  = p - 1;              // freed slot
            const int jw = j0 + 4 + s;         // == (jw & 3) slot-consistent
#pragma unroll
            for (int r = 0; r < 4; ++r) {
                const int u = tid + r * 512;
                if (u < 1920) {
                    const int pl = u / 640;
                    const int cu = u - pl * 640;
                    const short* src = xc + (size_t)((i + pl) * HP + jw) * PLANE + cu * 8;
                    gl_lds16(src, Sl + (size_t)(s * SLOT_SH) + (size_t)u * 8);
                }
            }
        }

        // ---- compute pixel p: lgkm-only waits ----
        f32x4 acc0 = z4, acc1 = z4, acc2 = z4, acc3 = z4, acc4 = z4;
        const short* bp = WL + (nt * 16 + l15) * FPAD + lg8;
#pragma unroll
        for (int kc = 0; kc < 9; ++kc) {
            const int kh   = kc / 3;
            const int kw   = kc - kh * 3;
            const int slot = (p + kw) & 3;
            const char* ab = (const char*)Sl + slot * (SLOT_SH * 2) + kh * (PLANE * 2);
            const bf16x8 b = *reinterpret_cast<const bf16x8*>(bp + kc * 32);
            const bf16x8 a0 = *reinterpret_cast<const bf16x8*>(ab + rowbyte[0]);
            const bf16x8 a1 = *reinterpret_cast<const bf16x8*>(ab + rowbyte[1]);
            const bf16x8 a2 = *reinterpret_cast<const bf16x8*>(ab + rowbyte[2]);
            const bf16x8 a3 = *reinterpret_cast<const bf16x8*>(ab + rowbyte[3]);
            const bf16x8 a4 = *reinterpret_cast<const bf16x8*>(ab + rowbyte[4]);
            acc0 = __builtin_amdgcn_mfma_f32_16x16x32_bf16(a0, b, acc0, 0, 0, 0);
            acc1 = __builtin_amdgcn_mfma_f32_16x16x32_bf16(a1, b, acc1, 0, 0, 0);
            acc2 = __builtin_amdgcn_mfma_f32_16x16x32_bf16(a2, b, acc2, 0, 0, 0);
            acc3 = __builtin_amdgcn_mfma_f32_16x16x32_bf16(a3, b, acc3, 0, 0, 0);
            acc4 = __builtin_amdgcn_mfma_f32_16x16x32_bf16(a4, b, acc4, 0, 0, 0);
        }

        // ---- store pixel p -> co[pix][o][bk] bf16 ----
        {
            const int pix = i * 32 + j0 + p;
            const int o3  = nt * 16 + l15;
            const size_t cb = ((size_t)pix * COUT + o3) * NBK + mh * 80 + lg * 4;
#define STORE1(a, mt) { s16x4 s_;                                          \
            s_.x = (short)f2bf(a[0]); s_.y = (short)f2bf(a[1]);            \
            s_.z = (short)f2bf(a[2]); s_.w = (short)f2bf(a[3]);            \
            *reinterpret_cast<s16x4*>(co + cb + (mt) * 16) = s_; }
            STORE1(acc0, 0) STORE1(acc1, 1) STORE1(acc2, 2)
            STORE1(acc3, 3) STORE1(acc4, 4)
#undef STORE1
        }
        __syncthreads();   // ends use of W-buf + slot; drains wv/gl_lds (done)
    }
#undef WLOAD
}

// ---- t2 ----
__global__ __launch_bounds__(256) void t2_kernel(
    const short* __restrict__ co,
    const float* __restrict__ bias,
    float* __restrict__ out)
{
    __shared__ short tl[32][36];
    const int b    = blockIdx.x;          // 10240 = o(64) * bkT(5) * pixT(32)
    const int o    = b & 63;
    const int rest = b >> 6;
    const int bkT  = rest % 5;
    const int pixT = rest / 5;
    const int tid  = threadIdx.x;
    {
        const int p  = tid >> 3;
        const int bq = tid & 7;
        const int pix = pixT * 32 + p;
        const s16x4 v = *reinterpret_cast<const s16x4*>(
            co + ((size_t)pix * COUT + o) * NBK + bkT * 32 + bq * 4);
        *reinterpret_cast<s16x4*>(&tl[p][bq * 4]) = v;
    }
    __syncthreads();
    {
        const int bb = tid >> 3;
        const int pq = tid & 7;
        const int bk = bkT * 32 + bb;
        const int k  = bk % 10;
        const size_t pbase = (size_t)pixT * 32 + pq * 4;
        const float4 bv = *reinterpret_cast<const float4*>(
            bias + ((size_t)(k * COUT + o) << 10) + pbase);
        float4 r;
        r.x = __uint_as_float(((unsigned)(unsigned short)tl[pq * 4 + 0][bb]) << 16) + bv.x;
        r.y = __uint_as_float(((unsigned)(unsigned short)tl[pq * 4 + 1][bb]) << 16) + bv.y;
        r.z = __uint_as_float(((unsigned)(unsigned short)tl[pq * 4 + 2][bb]) << 16) + bv.z;
        r.w = __uint_as_float(((unsigned)(unsigned short)tl[pq * 4 + 3][bb]) << 16) + bv.w;
        *reinterpret_cast<float4*>(out + ((size_t)(bk * COUT + o) << 10) + pbase) = r;
    }
}

// ================= R3 fallback (proven; needs 10 MB ws) =================
__global__ __launch_bounds__(256) void xpose_kernel(
    const float* __restrict__ x, short* __restrict__ xc)
{
    __shared__ short tile[HW][36];
    const int bid = blockIdx.x;
    const int bk  = bid >> 5;
    const int h   = bid & 31;
    const int tid = threadIdx.x;
    {
        const int c  = tid >> 3;
        const int w4 = (tid & 7) * 4;
        const float4 v = *reinterpret_cast<const float4*>(
            x + (size_t)(bk * 32 + c) * 1024 + h * 32 + w4);
        tile[w4 + 0][c] = (short)f2bf(v.x);
        tile[w4 + 1][c] = (short)f2bf(v.y);
        tile[w4 + 2][c] = (short)f2bf(v.z);
        tile[w4 + 3][c] = (short)f2bf(v.w);
    }
    __syncthreads();
    {
        const int w  = tid >> 3;
        const int cq = tid & 7;
        const uint2 pk = *reinterpret_cast<const uint2*>(&tile[w][cq * 4]);
        *reinterpret_cast<uint2*>(
            xc + ((size_t)(bk * 1024 + h * 32 + w) * 32 + cq * 4)) = pk;
    }
}

__global__ __launch_bounds__(512, 4) void local2d_mfma2_kernel(
    const short* __restrict__ xc,
    const float* __restrict__ w,
    const float* __restrict__ bias,
    float* __restrict__ out)
{
    __shared__ short Wl[COUT * FPAD];
    const int hb  = blockIdx.x;
    const int lb  = (hb & 7) * 128 + (hb >> 3);
    const int i   = lb >> 5;
    const int j   = lb & 31;
    const int pix = i * HW + j;
    const int tid = threadIdx.x;
    {
        const float* wp = w + (size_t)pix * (COUT * FDIM);
#pragma unroll
        for (int p = 0; p < 9; ++p) {
            const int g  = tid + p * 512;
            const int o  = g / 72;
            const int f4 = (g - o * 72) * 4;
            const float4 v = *reinterpret_cast<const float4*>(wp + o * FDIM + f4);
            const float vv[4] = {v.x, v.y, v.z, v.w};
            short* wrow = &Wl[o * FPAD];
#pragma unroll
            for (int e = 0; e < 4; ++e) {
                const int f    = f4 + e;
                const int c    = f / 9;
                const int cell = f - c * 9;
                wrow[cell * 32 + c] = (short)f2bf(vv[e]);
            }
        }
    }
    __syncthreads();
    const int wave = tid >> 6;
    const int lane = tid & 63;
    const int nt   = wave & 3;
    const int mh   = wave >> 2;
    const int l15  = lane & 15;
    const int lg8  = (lane >> 4) * 8;
    f32x4 acc[5];
#pragma unroll
    for (int mt = 0; mt < 5; ++mt)
#pragma unroll
        for (int r = 0; r < 4; ++r) acc[mt][r] = 0.f;
    const short* xb[5];
#pragma unroll
    for (int mt = 0; mt < 5; ++mt) {
        const int bk = mh * 80 + mt * 16 + l15;
        xb[mt] = xc + (size_t)bk * (HW * HW * CIN) + lg8;
    }
    const short* bp = &Wl[(nt * 16 + l15) * FPAD + lg8];
#pragma unroll
    for (int kc = 0; kc < 9; ++kc) {
        const int kh = kc / 3;
        const int kw = kc - kh * 3;
        const int ih = i - 1 + kh;
        const int jw = j - 1 + kw;
        if ((unsigned)ih >= (unsigned)HW || (unsigned)jw >= (unsigned)HW)
            continue;
        const bf16x8 b = *reinterpret_cast<const bf16x8*>(bp + kc * 32);
        const int xoff = (ih * HW + jw) * CIN;
#pragma unroll
        for (int mt = 0; mt < 5; ++mt) {
            const bf16x8 a = *reinterpret_cast<const bf16x8*>(xb[mt] + xoff);
            acc[mt] = __builtin_amdgcn_mfma_f32_16x16x32_bf16(a, b, acc[mt], 0, 0, 0);
        }
    }
    const int o  = nt * 16 + l15;
    const int r0 = (lane >> 4) * 4;
#pragma unroll
    for (int mt = 0; mt < 5; ++mt) {
        const int bk0 = mh * 80 + mt * 16 + r0;
#pragma unroll
        for (int r = 0; r < 4; ++r) {
            const int bk = bk0 + r;
            const int k  = bk % 10;
            out[((size_t)(bk * COUT + o) << 10) + pix] =
                acc[mt][r] + bias[((size_t)(k * COUT + o) << 10) + pix];
        }
    }
}

extern "C" void kernel_launch(void* const* d_in, const int* in_sizes, int n_in,
                              void* d_out, int out_size, void* d_ws, size_t ws_size,
                              hipStream_t stream) {
    const float* x    = (const float*)d_in[0];
    const float* w    = (const float*)d_in[1];
    const float* bias = (const float*)d_in[2];
    float* out        = (float*)d_out;

    if (ws_size >= XC_BYTES + CO_BYTES) {
        short* xc = (short*)d_ws;
        short* co = (short*)((char*)d_ws + XC_BYTES);
        hipLaunchKernelGGL(hz_kernel, dim3(132), dim3(256), 0, stream, xc);
        hipLaunchKernelGGL(t1_kernel, dim3(5120), dim3(256), 0, stream, x, xc);
        hipLaunchKernelGGL(local2d_main_kernel, dim3(256), dim3(512), 0, stream,
                           xc, w, co);
        hipLaunchKernelGGL(t2_kernel, dim3(10240), dim3(256), 0, stream,
                           co, bias, out);
    } else {
        short* xc = (short*)d_ws;
        hipLaunchKernelGGL(xpose_kernel, dim3(5120), dim3(256), 0, stream, x, xc);
        hipLaunchKernelGGL(local2d_mfma2_kernel, dim3(1024), dim3(512), 0, stream,
                           xc, w, bias, out);
    }
}